// Round 6
// baseline (40.412 us; speedup 1.0000x reference)
//
#include <hip/hip_runtime.h>

#define C_DIM 512
#define G_DIM 128
#define ROW_STRIDE 1536   // 3*C
#define CGROUPS 8         // 64-channel slices -> grid = 128*8 = 1024 blocks (4/CU)
#define NTHREADS 256      // 16 channel-threads (x float4 = 64 ch) x 16 row-replicas
#define RG 16             // row replicas per block
#define UNROLL 8

typedef float f4 __attribute__((ext_vector_type(4)));

__device__ __forceinline__ f4 ldnt(const float* p) {
    // streaming read-once data: nontemporal hint, don't pollute L2
    return __builtin_nontemporal_load(reinterpret_cast<const f4*>(p));
}

__device__ __forceinline__ void acc4(f4& s, f4& m, f4 v) {
    s += v;
    m[0] = fmaxf(m[0], v[0]); m[1] = fmaxf(m[1], v[1]);
    m[2] = fmaxf(m[2], v[2]); m[3] = fmaxf(m[3], v[3]);
}

// One block owns output row g, channels [cb*64, cb*64+64). Cooperative
// 3-round bracket search finds [start,end) for segment g (sorted batch),
// then a branch-free nontemporal stream + LDS tree reduce, single write.
// No atomics to global, no zero-init, no finalize pass, one dispatch.
__global__ __launch_bounds__(NTHREADS) void pool_owner_kernel(
        const float* __restrict__ x, const int* __restrict__ batch,
        float* __restrict__ out, int N) {
    const int g   = blockIdx.x >> 3;   // / CGROUPS
    const int cb  = blockIdx.x & 7;    // % CGROUPS
    const int tid = threadIdx.x;
    const int cg  = tid & 15;          // channel thread: owns 4 floats
    const int rg  = tid >> 4;          // row replica 0..15

    // ---- cooperative lower_bound for g (which=0) and g+1 (which=1) ----
    // Invariant: slo <= lb <= shi. Each round shrinks bracket to <= step.
    // 100000 -> 782 -> 7 -> exact after 3 rounds (step==1 covers bracket).
    __shared__ int slo[2], shi[2];
    if (tid < 2) { slo[tid] = 0; shi[tid] = N; }
    __syncthreads();
    {
        const int which  = tid >> 7;       // 128 threads per bound
        const int t      = tid & 127;
        const int target = g + which;
#pragma unroll
        for (int round = 0; round < 3; ++round) {
            const int L = slo[which], H = shi[which];
            const int sz = H - L;
            if (sz > 1) {
                const int step = (sz + 127) >> 7;   // ceil(sz/128)
                const int idx = L + t * step;
                if (idx < H) {
                    if (batch[idx] < target) atomicMax(&slo[which], idx + 1);
                    else                     atomicMin(&shi[which], idx);
                }
            }
            __syncthreads();
        }
    }
    const int start = slo[0];
    const int end   = slo[1];
    const int cnt   = end - start;

    f4 s = {0.f, 0.f, 0.f, 0.f};
    f4 m = {-INFINITY, -INFINITY, -INFINITY, -INFINITY};

    const float* base = x + (size_t)start * C_DIM + cb * 64 + cg * 4;

    // Branch-free stream: rows rg, rg+16, ...; unroll-8 keeps 8 independent
    // 16B loads (128 B/thread) in flight.
    int r = rg;
    for (; r + (UNROLL - 1) * RG < cnt; r += UNROLL * RG) {
        f4 v[UNROLL];
#pragma unroll
        for (int j = 0; j < UNROLL; ++j)
            v[j] = ldnt(base + (size_t)(r + j * RG) * C_DIM);
#pragma unroll
        for (int j = 0; j < UNROLL; ++j) acc4(s, m, v[j]);
    }
    for (; r < cnt; r += RG)
        acc4(s, m, ldnt(base + (size_t)r * C_DIM));

    // Reduce across the 16 row replicas in LDS (tree, conflict-free).
    __shared__ f4 ls[2][RG][16];   // [sum|max][rg][cg] = 8 KB
    ls[0][rg][cg] = s;
    ls[1][rg][cg] = m;
    __syncthreads();
#pragma unroll
    for (int off = RG / 2; off >= 1; off >>= 1) {
        if (rg < off) {
            f4 sa = ls[0][rg][cg], s2 = ls[0][rg + off][cg];
            f4 ma = ls[1][rg][cg], m2 = ls[1][rg + off][cg];
            sa += s2;
            ma[0] = fmaxf(ma[0], m2[0]); ma[1] = fmaxf(ma[1], m2[1]);
            ma[2] = fmaxf(ma[2], m2[2]); ma[3] = fmaxf(ma[3], m2[3]);
            ls[0][rg][cg] = sa;
            ls[1][rg][cg] = ma;
        }
        __syncthreads();
    }

    if (rg == 0) {
        f4 fs = ls[0][0][cg];
        f4 fm = ls[1][0][cg];
        const float inv = 1.0f / (float)max(cnt, 1);
        if (cnt == 0) fm = (f4){0.f, 0.f, 0.f, 0.f};  // torch_geometric: 0 for empty
        f4 mean = fs * inv;
        float* row = out + (size_t)g * ROW_STRIDE + cb * 64 + cg * 4;
        *reinterpret_cast<f4*>(row)        = mean;
        *reinterpret_cast<f4*>(row + 512)  = fm;
        *reinterpret_cast<f4*>(row + 1024) = fs;
    }
}

extern "C" void kernel_launch(void* const* d_in, const int* in_sizes, int n_in,
                              void* d_out, int out_size, void* d_ws, size_t ws_size,
                              hipStream_t stream) {
    const float* x     = (const float*)d_in[0];
    const int*   batch = (const int*)d_in[1];
    float* out = (float*)d_out;
    int N = in_sizes[0] / C_DIM;

    pool_owner_kernel<<<G_DIM * CGROUPS, NTHREADS, 0, stream>>>(x, batch, out, N);
}